// Round 1
// baseline (1334.401 us; speedup 1.0000x reference)
//
#include <hip/hip_runtime.h>

#define NN 100000
#define NE 3200000
#define FIN 128
#define FH 64
#define FO 64
#define NG 128

// ---------------- init: zero counters + output ----------------
__global__ void k_init(int* __restrict__ cnt, int* __restrict__ cursor,
                       int* __restrict__ root_idx, int* __restrict__ gcnt,
                       float* __restrict__ out) {
  int i = blockIdx.x * blockDim.x + threadIdx.x;
  if (i < NN) { cnt[i] = 0; cursor[i] = 0; }
  if (i < NG) { root_idx[i] = NN - 1; gcnt[i] = 0; }
  if (i < NG * (FO + FH)) out[i] = 0.0f;
}

// ---------------- degree count over dst ----------------
__global__ void k_count(const int* __restrict__ ei, int* __restrict__ cnt) {
  int e = blockIdx.x * blockDim.x + threadIdx.x;
  if (e < NE) atomicAdd(&cnt[ei[NE + e]], 1);
}

// ---------------- single-block exclusive scan -> rowptr, plus dinv ----------------
__global__ __launch_bounds__(1024) void k_scan(const int* __restrict__ cnt,
                                               int* __restrict__ rowptr,
                                               float* __restrict__ dinv) {
  __shared__ int part[1024];
  int tid = threadIdx.x;
  const int PER = (NN + 1023) / 1024;
  int start = tid * PER;
  int end = start + PER;
  if (end > NN) end = NN;
  if (start > NN) start = NN;
  int s = 0;
  for (int i = start; i < end; ++i) s += cnt[i];
  part[tid] = s;
  __syncthreads();
  for (int d = 1; d < 1024; d <<= 1) {
    int t = (tid >= d) ? part[tid - d] : 0;
    __syncthreads();
    part[tid] += t;
    __syncthreads();
  }
  int off = part[tid] - s;  // exclusive prefix
  for (int i = start; i < end; ++i) {
    rowptr[i] = off;
    off += cnt[i];
    dinv[i] = rsqrtf((float)cnt[i] + 1.0f);
  }
  if (tid == 1023) rowptr[NN] = part[1023];
}

// ---------------- scatter edges into CSR (by dst) ----------------
__global__ void k_scatter(const int* __restrict__ ei, const int* __restrict__ rowptr,
                          int* __restrict__ cursor, int* __restrict__ csr_src) {
  int e = blockIdx.x * blockDim.x + threadIdx.x;
  if (e < NE) {
    int s = ei[e];
    int d = ei[NE + e];
    int pos = atomicAdd(&cursor[d], 1);
    csr_src[rowptr[d] + pos] = s;
  }
}

// ---------------- GEMM1: h = x @ W1   [N,128]@[128,64] ----------------
__global__ __launch_bounds__(256) void k_gemm1(const float* __restrict__ x,
                                               const float* __restrict__ W1,
                                               float* __restrict__ h) {
  __shared__ float Ws[FIN * FH];   // 32 KB
  __shared__ float Xs[16 * FIN];   // 8 KB
  int tid = threadIdx.x;
  for (int i = tid; i < FIN * FH; i += 256) Ws[i] = W1[i];
  long n0 = (long)blockIdx.x * 16;
  const float4* xg = (const float4*)(x + n0 * FIN);
  float4* xs4 = (float4*)Xs;
  for (int i = tid; i < 16 * FIN / 4; i += 256) xs4[i] = xg[i];
  __syncthreads();
  int f = tid & 63;
  int nl = tid >> 6;  // 0..3
  int b = nl * 4;     // 4 nodes per thread
  float acc0 = 0.f, acc1 = 0.f, acc2 = 0.f, acc3 = 0.f;
  #pragma unroll 4
  for (int i = 0; i < FIN; i += 4) {
    float4 x0 = *(const float4*)&Xs[(b + 0) * FIN + i];
    float4 x1 = *(const float4*)&Xs[(b + 1) * FIN + i];
    float4 x2 = *(const float4*)&Xs[(b + 2) * FIN + i];
    float4 x3 = *(const float4*)&Xs[(b + 3) * FIN + i];
    float w0 = Ws[(i + 0) * FH + f];
    float w1 = Ws[(i + 1) * FH + f];
    float w2 = Ws[(i + 2) * FH + f];
    float w3 = Ws[(i + 3) * FH + f];
    acc0 += x0.x * w0 + x0.y * w1 + x0.z * w2 + x0.w * w3;
    acc1 += x1.x * w0 + x1.y * w1 + x1.z * w2 + x1.w * w3;
    acc2 += x2.x * w0 + x2.y * w1 + x2.z * w2 + x2.w * w3;
    acc3 += x3.x * w0 + x3.y * w1 + x3.z * w2 + x3.w * w3;
  }
  h[(n0 + b + 0) * FH + f] = acc0;
  h[(n0 + b + 1) * FH + f] = acc1;
  h[(n0 + b + 2) * FH + f] = acc2;
  h[(n0 + b + 3) * FH + f] = acc3;
}

// ---------------- root indices + graph node counts ----------------
__global__ void k_root(const int* __restrict__ batch, int* __restrict__ root_idx,
                       int* __restrict__ gcnt) {
  int n = blockIdx.x * blockDim.x + threadIdx.x;
  if (n < NN) {
    int g = batch[n];
    if (n == 0 || batch[n - 1] != g) root_idx[g] = n;  // batch sorted -> first occurrence
    atomicAdd(&gcnt[g], 1);
  }
}

// ---------------- per-graph root projection: relu(x[root]) @ W2[64:192,:] ----------------
__global__ __launch_bounds__(64) void k_rootproj(const float* __restrict__ x,
                                                 const float* __restrict__ W2,
                                                 const int* __restrict__ root_idx,
                                                 float* __restrict__ rp) {
  __shared__ float xr[FIN];
  int g = blockIdx.x;
  int t = threadIdx.x;
  long r = root_idx[g];
  xr[t]      = fmaxf(x[r * FIN + t], 0.0f);
  xr[t + 64] = fmaxf(x[r * FIN + t + 64], 0.0f);
  __syncthreads();
  float acc = 0.0f;
  #pragma unroll 8
  for (int i = 0; i < FIN; ++i) acc += xr[i] * W2[(FH + i) * FO + t];
  rp[g * FO + t] = acc;
}

// ---------------- aggregation: out[n] = dinv[n]*(sum_src h[s]*dinv[s] + h[n]*dinv[n]) + b ----------------
template <int RELU>
__global__ __launch_bounds__(256) void k_agg(const float* __restrict__ hsrc,
                                             const float* __restrict__ dinv,
                                             const int* __restrict__ rowptr,
                                             const int* __restrict__ csr_src,
                                             const float* __restrict__ bias,
                                             float* __restrict__ outb) {
  int wave = threadIdx.x >> 6;
  int lane = threadIdx.x & 63;
  int n = blockIdx.x * 4 + wave;
  if (n >= NN) return;
  float dn = dinv[n];
  float acc = hsrc[(long)n * FH + lane] * dn;  // self loop (gets *dn again below)
  int beg = rowptr[n], end = rowptr[n + 1];
  int e = beg;
  int s_next = (e < end) ? csr_src[e] : 0;
  for (; e < end; ++e) {
    int s = s_next;
    if (e + 1 < end) s_next = csr_src[e + 1];
    acc += hsrc[(long)s * FH + lane] * dinv[s];
  }
  float v = dn * acc + bias[lane];
  if (RELU) v = fmaxf(v, 0.0f);
  outb[(long)n * FH + lane] = v;
}

// ---------------- GEMM2: h2 = relu(h1) @ W2[0:64,:] + rp[batch] ----------------
__global__ __launch_bounds__(256) void k_gemm2(const float* __restrict__ h1,
                                               const float* __restrict__ W2,
                                               const float* __restrict__ rp,
                                               const int* __restrict__ batch,
                                               float* __restrict__ h2) {
  __shared__ float Ws[FH * FO];   // 16 KB (rows 0..63 of W2)
  __shared__ float Hs[16 * FH];   // 4 KB
  int tid = threadIdx.x;
  for (int i = tid; i < FH * FO; i += 256) Ws[i] = W2[i];
  long n0 = (long)blockIdx.x * 16;
  for (int i = tid; i < 16 * FH; i += 256) Hs[i] = fmaxf(h1[n0 * FH + i], 0.0f);
  __syncthreads();
  int f = tid & 63;
  int nl = tid >> 6;
  int b = nl * 4;
  float acc0 = rp[(long)batch[n0 + b + 0] * FO + f];
  float acc1 = rp[(long)batch[n0 + b + 1] * FO + f];
  float acc2 = rp[(long)batch[n0 + b + 2] * FO + f];
  float acc3 = rp[(long)batch[n0 + b + 3] * FO + f];
  #pragma unroll 4
  for (int j = 0; j < FH; j += 4) {
    float4 h0 = *(const float4*)&Hs[(b + 0) * FH + j];
    float4 h1v = *(const float4*)&Hs[(b + 1) * FH + j];
    float4 h2v = *(const float4*)&Hs[(b + 2) * FH + j];
    float4 h3 = *(const float4*)&Hs[(b + 3) * FH + j];
    float w0 = Ws[(j + 0) * FO + f];
    float w1 = Ws[(j + 1) * FO + f];
    float w2 = Ws[(j + 2) * FO + f];
    float w3 = Ws[(j + 3) * FO + f];
    acc0 += h0.x * w0 + h0.y * w1 + h0.z * w2 + h0.w * w3;
    acc1 += h1v.x * w0 + h1v.y * w1 + h1v.z * w2 + h1v.w * w3;
    acc2 += h2v.x * w0 + h2v.y * w1 + h2v.z * w2 + h2v.w * w3;
    acc3 += h3.x * w0 + h3.y * w1 + h3.z * w2 + h3.w * w3;
  }
  h2[(n0 + b + 0) * FH + f] = acc0;
  h2[(n0 + b + 1) * FH + f] = acc1;
  h2[(n0 + b + 2) * FH + f] = acc2;
  h2[(n0 + b + 3) * FH + f] = acc3;
}

// ---------------- mean-pool part 1: segment sums of r over batch ----------------
__global__ __launch_bounds__(64) void k_pool(const float* __restrict__ r,
                                             const int* __restrict__ batch,
                                             float* __restrict__ out) {
  const int PC = 100;
  int lane = threadIdx.x;
  long n0 = (long)blockIdx.x * PC;
  long n1 = n0 + PC;
  if (n1 > NN) n1 = NN;
  if (n0 >= NN) return;
  float acc = 0.0f;
  int cur = batch[n0];
  for (long n = n0; n < n1; ++n) {
    int g = batch[n];
    if (g != cur) {
      atomicAdd(&out[(long)cur * (FO + FH) + lane], acc);
      acc = 0.0f;
      cur = g;
    }
    acc += r[n * FH + lane];
  }
  atomicAdd(&out[(long)cur * (FO + FH) + lane], acc);
}

// ---------------- finalize: divide by count; fill root2 half ----------------
__global__ void k_final(float* __restrict__ out, const int* __restrict__ gcnt,
                        const int* __restrict__ root_idx, const float* __restrict__ h1full) {
  int i = blockIdx.x * blockDim.x + threadIdx.x;
  if (i >= NG * FO) return;
  int g = i >> 6, f = i & 63;
  int c = gcnt[g];
  float inv = 1.0f / fmaxf((float)c, 1.0f);
  out[g * (FO + FH) + f] *= inv;
  out[g * (FO + FH) + FO + f] = (c > 0) ? h1full[(long)root_idx[g] * FH + f] : 0.0f;
}

extern "C" void kernel_launch(void* const* d_in, const int* in_sizes, int n_in,
                              void* d_out, int out_size, void* d_ws, size_t ws_size,
                              hipStream_t stream) {
  const float* x   = (const float*)d_in[0];
  const int*   ei  = (const int*)d_in[1];   // [2,E] int32
  const int*   bat = (const int*)d_in[2];   // [N]  int32 (sorted)
  const float* W1  = (const float*)d_in[3];
  const float* b1  = (const float*)d_in[4];
  const float* W2  = (const float*)d_in[5];
  const float* b2  = (const float*)d_in[6];
  float* out = (float*)d_out;

  char* p = (char*)d_ws;
  auto carve = [&](size_t bytes) -> void* {
    char* q = p;
    p += (bytes + 511) & ~size_t(511);
    return (void*)q;
  };
  float* dinv    = (float*)carve((size_t)NN * 4);
  int*   cnt     = (int*)carve((size_t)NN * 4);
  int*   cursor  = (int*)carve((size_t)NN * 4);
  int*   rowptr  = (int*)carve((size_t)(NN + 1) * 4);
  int*   csr_src = (int*)carve((size_t)NE * 4);
  float* bufA    = (float*)carve((size_t)NN * FH * 4);  // h, later r
  float* bufB    = (float*)carve((size_t)NN * FH * 4);  // h1_full
  float* bufC    = (float*)carve((size_t)NN * FH * 4);  // h2
  int*   root_i  = (int*)carve((size_t)NG * 4);
  int*   gcnt    = (int*)carve((size_t)NG * 4);
  float* rp      = (float*)carve((size_t)NG * FO * 4);

  k_init<<<(NN + 255) / 256, 256, 0, stream>>>(cnt, cursor, root_i, gcnt, out);
  k_count<<<(NE + 255) / 256, 256, 0, stream>>>(ei, cnt);
  k_scan<<<1, 1024, 0, stream>>>(cnt, rowptr, dinv);
  k_scatter<<<(NE + 255) / 256, 256, 0, stream>>>(ei, rowptr, cursor, csr_src);
  k_gemm1<<<NN / 16, 256, 0, stream>>>(x, W1, bufA);
  k_root<<<(NN + 255) / 256, 256, 0, stream>>>(bat, root_i, gcnt);
  k_rootproj<<<NG, 64, 0, stream>>>(x, W2, root_i, rp);
  k_agg<0><<<(NN + 3) / 4, 256, 0, stream>>>(bufA, dinv, rowptr, csr_src, b1, bufB);
  k_gemm2<<<NN / 16, 256, 0, stream>>>(bufB, W2, rp, bat, bufC);
  k_agg<1><<<(NN + 3) / 4, 256, 0, stream>>>(bufC, dinv, rowptr, csr_src, b2, bufA);
  k_pool<<<(NN + 99) / 100, 64, 0, stream>>>(bufA, bat, out);
  k_final<<<(NG * FO + 255) / 256, 256, 0, stream>>>(out, gcnt, root_i, bufB);
}

// Round 2
// 1098.024 us; speedup vs baseline: 1.2153x; 1.2153x over previous
//
#include <hip/hip_runtime.h>

#define NN 100000
#define NE 3200000
#define FIN 128
#define FH 64
#define FO 64
#define NG 128

// ---------------- init: zero counters + output ----------------
__global__ void k_init(int* __restrict__ cnt, int* __restrict__ cursor,
                       float* __restrict__ out) {
  int i = blockIdx.x * blockDim.x + threadIdx.x;
  if (i < NN) { cnt[i] = 0; cursor[i] = 0; }
  if (i < NG * (FO + FH)) out[i] = 0.0f;
}

// ---------------- degree count over dst ----------------
__global__ void k_count(const int* __restrict__ ei, int* __restrict__ cnt) {
  int e = blockIdx.x * blockDim.x + threadIdx.x;
  if (e < NE) atomicAdd(&cnt[ei[NE + e]], 1);
}

// ---------------- single-block exclusive scan -> rowptr, plus dinv ----------------
__global__ __launch_bounds__(1024) void k_scan(const int* __restrict__ cnt,
                                               int* __restrict__ rowptr,
                                               float* __restrict__ dinv) {
  __shared__ int part[1024];
  int tid = threadIdx.x;
  const int PER = (NN + 1023) / 1024;
  int start = tid * PER;
  int end = start + PER;
  if (end > NN) end = NN;
  if (start > NN) start = NN;
  int s = 0;
  for (int i = start; i < end; ++i) s += cnt[i];
  part[tid] = s;
  __syncthreads();
  for (int d = 1; d < 1024; d <<= 1) {
    int t = (tid >= d) ? part[tid - d] : 0;
    __syncthreads();
    part[tid] += t;
    __syncthreads();
  }
  int off = part[tid] - s;  // exclusive prefix
  for (int i = start; i < end; ++i) {
    rowptr[i] = off;
    off += cnt[i];
    dinv[i] = rsqrtf((float)cnt[i] + 1.0f);
  }
  if (tid == 1023) rowptr[NN] = part[1023];
}

// ---------------- scatter edges into CSR (by dst) ----------------
__global__ void k_scatter(const int* __restrict__ ei, const int* __restrict__ rowptr,
                          int* __restrict__ cursor, int* __restrict__ csr_src) {
  int e = blockIdx.x * blockDim.x + threadIdx.x;
  if (e < NE) {
    int s = ei[e];
    int d = ei[NE + e];
    int pos = atomicAdd(&cursor[d], 1);
    csr_src[rowptr[d] + pos] = s;
  }
}

// ---------------- root indices + graph node counts via binary search ----------------
// batch is sorted; 128 threads, each does two lower_bounds (~17 iters).
__global__ __launch_bounds__(128) void k_root(const int* __restrict__ batch,
                                              int* __restrict__ root_idx,
                                              int* __restrict__ gcnt) {
  int g = threadIdx.x;
  if (g >= NG) return;
  // lower_bound for g
  int lo = 0, hi = NN;
  while (lo < hi) { int m = (lo + hi) >> 1; if (batch[m] < g) lo = m + 1; else hi = m; }
  int a = lo;
  // lower_bound for g+1
  lo = a; hi = NN;
  while (lo < hi) { int m = (lo + hi) >> 1; if (batch[m] < g + 1) lo = m + 1; else hi = m; }
  int b = lo;
  gcnt[g] = b - a;
  root_idx[g] = (b > a) ? a : (NN - 1);
}

// ---------------- GEMM1: h = x @ W1   [N,128]@[128,64] ----------------
__global__ __launch_bounds__(256) void k_gemm1(const float* __restrict__ x,
                                               const float* __restrict__ W1,
                                               float* __restrict__ h) {
  __shared__ float Ws[FIN * FH];   // 32 KB
  __shared__ float Xs[16 * FIN];   // 8 KB
  int tid = threadIdx.x;
  for (int i = tid; i < FIN * FH; i += 256) Ws[i] = W1[i];
  long n0 = (long)blockIdx.x * 16;
  const float4* xg = (const float4*)(x + n0 * FIN);
  float4* xs4 = (float4*)Xs;
  for (int i = tid; i < 16 * FIN / 4; i += 256) xs4[i] = xg[i];
  __syncthreads();
  int f = tid & 63;
  int nl = tid >> 6;  // 0..3
  int b = nl * 4;     // 4 nodes per thread
  float acc0 = 0.f, acc1 = 0.f, acc2 = 0.f, acc3 = 0.f;
  #pragma unroll 4
  for (int i = 0; i < FIN; i += 4) {
    float4 x0 = *(const float4*)&Xs[(b + 0) * FIN + i];
    float4 x1 = *(const float4*)&Xs[(b + 1) * FIN + i];
    float4 x2 = *(const float4*)&Xs[(b + 2) * FIN + i];
    float4 x3 = *(const float4*)&Xs[(b + 3) * FIN + i];
    float w0 = Ws[(i + 0) * FH + f];
    float w1 = Ws[(i + 1) * FH + f];
    float w2 = Ws[(i + 2) * FH + f];
    float w3 = Ws[(i + 3) * FH + f];
    acc0 += x0.x * w0 + x0.y * w1 + x0.z * w2 + x0.w * w3;
    acc1 += x1.x * w0 + x1.y * w1 + x1.z * w2 + x1.w * w3;
    acc2 += x2.x * w0 + x2.y * w1 + x2.z * w2 + x2.w * w3;
    acc3 += x3.x * w0 + x3.y * w1 + x3.z * w2 + x3.w * w3;
  }
  h[(n0 + b + 0) * FH + f] = acc0;
  h[(n0 + b + 1) * FH + f] = acc1;
  h[(n0 + b + 2) * FH + f] = acc2;
  h[(n0 + b + 3) * FH + f] = acc3;
}

// ---------------- per-graph root projection: relu(x[root]) @ W2[64:192,:] ----------------
__global__ __launch_bounds__(64) void k_rootproj(const float* __restrict__ x,
                                                 const float* __restrict__ W2,
                                                 const int* __restrict__ root_idx,
                                                 float* __restrict__ rp) {
  __shared__ float xr[FIN];
  int g = blockIdx.x;
  int t = threadIdx.x;
  long r = root_idx[g];
  xr[t]      = fmaxf(x[r * FIN + t], 0.0f);
  xr[t + 64] = fmaxf(x[r * FIN + t + 64], 0.0f);
  __syncthreads();
  float acc = 0.0f;
  #pragma unroll 8
  for (int i = 0; i < FIN; ++i) acc += xr[i] * W2[(FH + i) * FO + t];
  rp[g * FO + t] = acc;
}

// ---------------- aggregation: out[n] = dinv[n]*(sum_src h[s]*dinv[s] + h[n]*dinv[n]) + b ----------------
template <int RELU>
__global__ __launch_bounds__(256) void k_agg(const float* __restrict__ hsrc,
                                             const float* __restrict__ dinv,
                                             const int* __restrict__ rowptr,
                                             const int* __restrict__ csr_src,
                                             const float* __restrict__ bias,
                                             float* __restrict__ outb) {
  int wave = threadIdx.x >> 6;
  int lane = threadIdx.x & 63;
  int n = blockIdx.x * 4 + wave;
  if (n >= NN) return;
  float dn = dinv[n];
  float acc = hsrc[(long)n * FH + lane] * dn;  // self loop (gets *dn again below)
  int beg = rowptr[n], end = rowptr[n + 1];
  int e = beg;
  int s_next = (e < end) ? csr_src[e] : 0;
  for (; e < end; ++e) {
    int s = s_next;
    if (e + 1 < end) s_next = csr_src[e + 1];
    acc += hsrc[(long)s * FH + lane] * dinv[s];
  }
  float v = dn * acc + bias[lane];
  if (RELU) v = fmaxf(v, 0.0f);
  outb[(long)n * FH + lane] = v;
}

// ---------------- GEMM2: h2 = relu(h1) @ W2[0:64,:] + rp[batch] ----------------
__global__ __launch_bounds__(256) void k_gemm2(const float* __restrict__ h1,
                                               const float* __restrict__ W2,
                                               const float* __restrict__ rp,
                                               const int* __restrict__ batch,
                                               float* __restrict__ h2) {
  __shared__ float Ws[FH * FO];   // 16 KB (rows 0..63 of W2)
  __shared__ float Hs[16 * FH];   // 4 KB
  int tid = threadIdx.x;
  for (int i = tid; i < FH * FO; i += 256) Ws[i] = W2[i];
  long n0 = (long)blockIdx.x * 16;
  for (int i = tid; i < 16 * FH; i += 256) Hs[i] = fmaxf(h1[n0 * FH + i], 0.0f);
  __syncthreads();
  int f = tid & 63;
  int nl = tid >> 6;
  int b = nl * 4;
  float acc0 = rp[(long)batch[n0 + b + 0] * FO + f];
  float acc1 = rp[(long)batch[n0 + b + 1] * FO + f];
  float acc2 = rp[(long)batch[n0 + b + 2] * FO + f];
  float acc3 = rp[(long)batch[n0 + b + 3] * FO + f];
  #pragma unroll 4
  for (int j = 0; j < FH; j += 4) {
    float4 h0 = *(const float4*)&Hs[(b + 0) * FH + j];
    float4 h1v = *(const float4*)&Hs[(b + 1) * FH + j];
    float4 h2v = *(const float4*)&Hs[(b + 2) * FH + j];
    float4 h3 = *(const float4*)&Hs[(b + 3) * FH + j];
    float w0 = Ws[(j + 0) * FO + f];
    float w1 = Ws[(j + 1) * FO + f];
    float w2 = Ws[(j + 2) * FO + f];
    float w3 = Ws[(j + 3) * FO + f];
    acc0 += h0.x * w0 + h0.y * w1 + h0.z * w2 + h0.w * w3;
    acc1 += h1v.x * w0 + h1v.y * w1 + h1v.z * w2 + h1v.w * w3;
    acc2 += h2v.x * w0 + h2v.y * w1 + h2v.z * w2 + h2v.w * w3;
    acc3 += h3.x * w0 + h3.y * w1 + h3.z * w2 + h3.w * w3;
  }
  h2[(n0 + b + 0) * FH + f] = acc0;
  h2[(n0 + b + 1) * FH + f] = acc1;
  h2[(n0 + b + 2) * FH + f] = acc2;
  h2[(n0 + b + 3) * FH + f] = acc3;
}

// ---------------- mean-pool part 1: segment sums of r over batch ----------------
__global__ __launch_bounds__(64) void k_pool(const float* __restrict__ r,
                                             const int* __restrict__ batch,
                                             float* __restrict__ out) {
  const int PC = 100;
  int lane = threadIdx.x;
  long n0 = (long)blockIdx.x * PC;
  long n1 = n0 + PC;
  if (n1 > NN) n1 = NN;
  if (n0 >= NN) return;
  float acc = 0.0f;
  int cur = batch[n0];
  for (long n = n0; n < n1; ++n) {
    int g = batch[n];
    if (g != cur) {
      atomicAdd(&out[(long)cur * (FO + FH) + lane], acc);
      acc = 0.0f;
      cur = g;
    }
    acc += r[n * FH + lane];
  }
  atomicAdd(&out[(long)cur * (FO + FH) + lane], acc);
}

// ---------------- finalize: divide by count; fill root2 half ----------------
__global__ void k_final(float* __restrict__ out, const int* __restrict__ gcnt,
                        const int* __restrict__ root_idx, const float* __restrict__ h1full) {
  int i = blockIdx.x * blockDim.x + threadIdx.x;
  if (i >= NG * FO) return;
  int g = i >> 6, f = i & 63;
  int c = gcnt[g];
  float inv = 1.0f / fmaxf((float)c, 1.0f);
  out[g * (FO + FH) + f] *= inv;
  out[g * (FO + FH) + FO + f] = (c > 0) ? h1full[(long)root_idx[g] * FH + f] : 0.0f;
}

extern "C" void kernel_launch(void* const* d_in, const int* in_sizes, int n_in,
                              void* d_out, int out_size, void* d_ws, size_t ws_size,
                              hipStream_t stream) {
  const float* x   = (const float*)d_in[0];
  const int*   ei  = (const int*)d_in[1];   // [2,E] int32
  const int*   bat = (const int*)d_in[2];   // [N]  int32 (sorted)
  const float* W1  = (const float*)d_in[3];
  const float* b1  = (const float*)d_in[4];
  const float* W2  = (const float*)d_in[5];
  const float* b2  = (const float*)d_in[6];
  float* out = (float*)d_out;

  char* p = (char*)d_ws;
  auto carve = [&](size_t bytes) -> void* {
    char* q = p;
    p += (bytes + 511) & ~size_t(511);
    return (void*)q;
  };
  float* dinv    = (float*)carve((size_t)NN * 4);
  int*   cnt     = (int*)carve((size_t)NN * 4);
  int*   cursor  = (int*)carve((size_t)NN * 4);
  int*   rowptr  = (int*)carve((size_t)(NN + 1) * 4);
  int*   csr_src = (int*)carve((size_t)NE * 4);
  float* bufA    = (float*)carve((size_t)NN * FH * 4);  // h, later r
  float* bufB    = (float*)carve((size_t)NN * FH * 4);  // h1_full
  float* bufC    = (float*)carve((size_t)NN * FH * 4);  // h2
  int*   root_i  = (int*)carve((size_t)NG * 4);
  int*   gcnt    = (int*)carve((size_t)NG * 4);
  float* rp      = (float*)carve((size_t)NG * FO * 4);

  k_init<<<(NN + 255) / 256, 256, 0, stream>>>(cnt, cursor, out);
  k_count<<<(NE + 255) / 256, 256, 0, stream>>>(ei, cnt);
  k_scan<<<1, 1024, 0, stream>>>(cnt, rowptr, dinv);
  k_scatter<<<(NE + 255) / 256, 256, 0, stream>>>(ei, rowptr, cursor, csr_src);
  k_gemm1<<<NN / 16, 256, 0, stream>>>(x, W1, bufA);
  k_root<<<1, 128, 0, stream>>>(bat, root_i, gcnt);
  k_rootproj<<<NG, 64, 0, stream>>>(x, W2, root_i, rp);
  k_agg<0><<<(NN + 3) / 4, 256, 0, stream>>>(bufA, dinv, rowptr, csr_src, b1, bufB);
  k_gemm2<<<NN / 16, 256, 0, stream>>>(bufB, W2, rp, bat, bufC);
  k_agg<1><<<(NN + 3) / 4, 256, 0, stream>>>(bufC, dinv, rowptr, csr_src, b2, bufA);
  k_pool<<<(NN + 99) / 100, 64, 0, stream>>>(bufA, bat, out);
  k_final<<<(NG * FO + 255) / 256, 256, 0, stream>>>(out, gcnt, root_i, bufB);
}